// Round 7
// baseline (305.234 us; speedup 1.0000x reference)
//
#include <hip/hip_runtime.h>

// Register-resident fused-16 Jacobi, v9: v8 + wE contraction (state 96->80).
//  - v8 ground truth: WRITE still 58MB (+24.5 over logical), VGPR_Count=64,
//    dur 104.6 ~= v7. waves_per_eu(4,4) granted the 128 unified budget but
//    true pressure (~150: 96 persistent + transients + pointers) still
//    exceeds it -> real scratch. Occupancy lever exhausted; shrink the state.
//  - v9 drops wE via the convex-weight identity wN+wS+wW+wE == 1:
//      u' = (Fc + uE) + wN*(uN-uE) + wS*(uS-uE) + wW*(uW-uE)
//    (v3's verified formulation). Persistent 80 floats -> peak ~110 < 128.
//  - OOB points must stay 0 (implicit wE=1 would leak uE): per-step mask
//    multiply, masks precomputed ONLY in the block-uniform slow path
//    (boundary tiles); weights at OOB points zeroed (avoids frcp(0) NaN).
//    Fast blocks: no masks, no extra ops beyond the 3-sub/1-add reshape.
//  - everything else identical to v8: tile 128x128, 16 waves, lane owns
//    2 cols, rolling 3-row kappa window, DPP W/E (garbage halo-tight at
//    cols 0/127), dbuf LDS strip exchange (32KB), one barrier/step,
//    row-reordered step body (rows 1..6 first), output rel [16,112)^2.

namespace {
constexpr int    G    = 1024, Ni = 1022;
constexpr int    TOUT = 96, HALO = 16;          // tile 128
constexpr size_t IMG_K = (size_t)G * G;
constexpr size_t IMG_P = (size_t)Ni * Ni;
constexpr float  H2 = (float)(1.0 / (1023.0 * 1023.0));
}

__device__ __forceinline__ float frcp(float x) { return __builtin_amdgcn_rcpf(x); }

// lane l <- lane l-1 (wave_shr1); shifted-in lane gets 0 (bound_ctrl)
__device__ __forceinline__ float lane_shr1(float x) {
    return __builtin_bit_cast(float,
        __builtin_amdgcn_update_dpp(0, __builtin_bit_cast(int, x), 0x138, 0xF, 0xF, true));
}
// lane l <- lane l+1 (wave_shl1)
__device__ __forceinline__ float lane_shl1(float x) {
    return __builtin_bit_cast(float,
        __builtin_amdgcn_update_dpp(0, __builtin_bit_cast(int, x), 0x130, 0xF, 0xF, true));
}

__global__ __launch_bounds__(1024)
__attribute__((amdgpu_waves_per_eu(4, 4)))
void jac_fused16(const float* __restrict__ pre, float* __restrict__ out,
                 const float* __restrict__ kap, const float* __restrict__ fin)
{
    __shared__ float2 ex[2][2][1024];            // [buf][top/bot][tid] = 32 KB

    const int tid = threadIdx.x;
    const int w = tid >> 6, l = tid & 63;        // wave id (0..15), lane id
    const int bx = blockIdx.x, by = blockIdx.y, b = blockIdx.z;
    const int X0 = bx * TOUT - HALO, Y0 = by * TOUT - HALO;
    const int c0 = X0 + 2 * l;                   // lane's first column (even)
    const int gy0 = Y0 + 8 * w;                  // wave's first row

    const float* kB = kap + (size_t)b * IMG_K;
    const float* fB = fin + (size_t)b * IMG_K;
    const bool fast = (bx >= 1) && (bx <= 9) && (by >= 1) && (by <= 9);

    // ---- weights via rolling 3-row kappa window; wE implicit (sum==1) ----
    float2 wN[8], wS[8], wW[8], Fc[8];
    float2 mk[8];                                // OOB masks, slow path only
    if (fast) {                                  // all accesses in-bounds
        const float* kp = kB + (size_t)gy0 * G + c0;
        const float* fp = fB + (size_t)(gy0 + 1) * G + c0;
        float2 q0 = *(const float2*)kp;          // kappa row gy0,   cols c0,c0+1
        float2 q1 = *(const float2*)(kp + G);    // kappa row gy0+1
        float  e0 = lane_shl1(q0.x);             // kappa[gy0,   c0+2]
        float  e1 = lane_shl1(q1.x);             // kappa[gy0+1, c0+2]
        #pragma unroll
        for (int r = 0; r < 8; ++r) {
            const float2 q2 = *(const float2*)(kp + (size_t)(r + 2) * G);
            const float  e2 = lane_shl1(q2.x);
            const float2 fr = *(const float2*)(fp + (size_t)r * G);
            const float f0 = fr.y, f1 = lane_shl1(fr.x);
            const float ke1 = lane_shl1(q1.y);   // kappa[gy+1, c0+3]
            const float inv0 = frcp(2.0f * q1.y + 0.5f * (q0.y + q2.y + q1.x + e1));
            const float inv1 = frcp(2.0f * e1   + 0.5f * (e0 + e2 + q1.y + ke1));
            wN[r] = make_float2(0.5f * (q1.y + q0.y) * inv0, 0.5f * (e1 + e0) * inv1);
            wS[r] = make_float2(0.5f * (q1.y + q2.y) * inv0, 0.5f * (e1 + e2) * inv1);
            wW[r] = make_float2(0.5f * (q1.y + q1.x) * inv0, 0.5f * (e1 + q1.y) * inv1);
            Fc[r] = make_float2(f0 * H2 * inv0, f1 * H2 * inv1);
            q0 = q1; q1 = q2; e0 = e1; e1 = e2;
        }
    } else {
        auto gk = [&](int ry, int cx) -> float {
            return ((unsigned)ry < (unsigned)G && (unsigned)cx < (unsigned)G)
                 ? kB[(size_t)ry * G + cx] : 0.0f;
        };
        const float cm0 = ((unsigned)c0       < (unsigned)Ni) ? 1.0f : 0.0f;
        const float cm1 = ((unsigned)(c0 + 1) < (unsigned)Ni) ? 1.0f : 0.0f;
        float qx0 = gk(gy0,     c0), qy0 = gk(gy0,     c0 + 1);
        float qx1 = gk(gy0 + 1, c0), qy1 = gk(gy0 + 1, c0 + 1);
        float e0 = lane_shl1(qx0), e1 = lane_shl1(qx1);
        #pragma unroll
        for (int r = 0; r < 8; ++r) {
            const float qx2 = gk(gy0 + r + 2, c0), qy2 = gk(gy0 + r + 2, c0 + 1);
            const float e2 = lane_shl1(qx2);
            const int ry = gy0 + 1 + r;
            const bool rv = (unsigned)ry < (unsigned)G;
            const float fa = (rv && (unsigned)c0       < (unsigned)G) ? fB[(size_t)ry * G + c0]     : 0.0f;
            const float fb = (rv && (unsigned)(c0 + 1) < (unsigned)G) ? fB[(size_t)ry * G + c0 + 1] : 0.0f;
            const float f0 = fb, f1 = lane_shl1(fa);
            const float ke1 = lane_shl1(qy1);
            const float inv0 = frcp(2.0f * qy1 + 0.5f * (qy0 + qy2 + qx1 + e1));
            const float inv1 = frcp(2.0f * e1  + 0.5f * (e0 + e2 + qy1 + ke1));
            const int gy = gy0 + r;
            const bool dr = (unsigned)gy < (unsigned)Ni;
            const bool d0 = dr && (unsigned)c0       < (unsigned)Ni;
            const bool d1 = dr && (unsigned)(c0 + 1) < (unsigned)Ni;
            // weights zeroed at OOB points (inv may be inf -> avoid NaN)
            wN[r] = make_float2(d0 ? 0.5f * (qy1 + qy0) * inv0 : 0.0f,
                                d1 ? 0.5f * (e1 + e0)   * inv1 : 0.0f);
            wS[r] = make_float2(d0 ? 0.5f * (qy1 + qy2) * inv0 : 0.0f,
                                d1 ? 0.5f * (e1 + e2)   * inv1 : 0.0f);
            wW[r] = make_float2(d0 ? 0.5f * (qy1 + qx1) * inv0 : 0.0f,
                                d1 ? 0.5f * (e1 + qy1)  * inv1 : 0.0f);
            Fc[r] = make_float2(d0 ? f0 * H2 * inv0 : 0.0f,
                                d1 ? f1 * H2 * inv1 : 0.0f);
            const float rmr = dr ? 1.0f : 0.0f;
            mk[r] = make_float2(rmr * cm0, rmr * cm1);
            qx0 = qx1; qy0 = qy1; qx1 = qx2; qy1 = qy2; e0 = e1; e1 = e2;
        }
    }

    // ---- u patch (loaded after weights: kappa/f transients are dead) ----
    float2 u[8];
    if (fast) {
        const float* uS = pre + (size_t)b * IMG_P + (size_t)gy0 * Ni + c0;
        #pragma unroll
        for (int r = 0; r < 8; ++r) u[r] = *(const float2*)(uS + (size_t)r * Ni);
    } else {
        const float* uS = pre + (size_t)b * IMG_P;
        #pragma unroll
        for (int r = 0; r < 8; ++r) {
            const int gy = gy0 + r;
            const bool rv = (unsigned)gy < (unsigned)Ni;
            const float a = (rv && (unsigned)c0       < (unsigned)Ni) ? uS[(size_t)gy * Ni + c0]     : 0.0f;
            const float q = (rv && (unsigned)(c0 + 1) < (unsigned)Ni) ? uS[(size_t)gy * Ni + c0 + 1] : 0.0f;
            u[r] = make_float2(a, q);
        }
    }

    // ---- 16 steps; N/S in regs, W/E via DPP, strip edges via dbuf LDS.
    //      u' = (Fc+uE) + wN*(uN-uE) + wS*(uS-uE) + wW*(uW-uE); masked blocks
    //      multiply by mk to keep OOB points at 0 (implicit wE would leak). ----
    const int iN = (w > 0)  ? tid - 64 : tid;     // wave w-1's bottom row (clamp: halo-safe)
    const int iS = (w < 15) ? tid + 64 : tid;     // wave w+1's top row

    auto run = [&](bool masked) {
        #pragma unroll
        for (int t = 0; t < 16; ++t) {
            float2* top = ex[t & 1][0];
            float2* bot = ex[t & 1][1];
            top[tid] = u[0];
            bot[tid] = u[7];
            __syncthreads();
            const float2 hN = bot[iN];            // consumed only at row 0
            const float2 hS = top[iS];            // consumed only at row 7
            const float2 o1s = u[1], o6s = u[6];  // old values for rows 0/7
            float2 pn = u[0];
            #pragma unroll
            for (int r = 1; r < 7; ++r) {         // register-only rows
                const float2 s = u[r + 1];        // old (ascending order)
                const float o0 = u[r].x, o1 = u[r].y;
                const float uWh = lane_shr1(o1);
                const float uEh = lane_shl1(o0);
                float v0 = fmaf(wW[r].x, uWh - o1,
                           fmaf(wS[r].x, s.x - o1,
                           fmaf(wN[r].x, pn.x - o1, Fc[r].x + o1)));
                float v1 = fmaf(wW[r].y, o0 - uEh,
                           fmaf(wS[r].y, s.y - uEh,
                           fmaf(wN[r].y, pn.y - uEh, Fc[r].y + uEh)));
                if (masked) { v0 *= mk[r].x; v1 *= mk[r].y; }
                pn = make_float2(o0, o1);
                u[r] = make_float2(v0, v1);
            }
            {   // row 0: N = hN, S = old u[1]
                const float o0 = u[0].x, o1 = u[0].y;
                const float uWh = lane_shr1(o1);
                const float uEh = lane_shl1(o0);
                float v0 = fmaf(wW[0].x, uWh - o1,
                           fmaf(wS[0].x, o1s.x - o1,
                           fmaf(wN[0].x, hN.x - o1, Fc[0].x + o1)));
                float v1 = fmaf(wW[0].y, o0 - uEh,
                           fmaf(wS[0].y, o1s.y - uEh,
                           fmaf(wN[0].y, hN.y - uEh, Fc[0].y + uEh)));
                if (masked) { v0 *= mk[0].x; v1 *= mk[0].y; }
                u[0] = make_float2(v0, v1);
            }
            {   // row 7: N = old u[6], S = hS
                const float o0 = u[7].x, o1 = u[7].y;
                const float uWh = lane_shr1(o1);
                const float uEh = lane_shl1(o0);
                float v0 = fmaf(wW[7].x, uWh - o1,
                           fmaf(wS[7].x, hS.x - o1,
                           fmaf(wN[7].x, o6s.x - o1, Fc[7].x + o1)));
                float v1 = fmaf(wW[7].y, o0 - uEh,
                           fmaf(wS[7].y, hS.y - uEh,
                           fmaf(wN[7].y, o6s.y - uEh, Fc[7].y + uEh)));
                if (masked) { v0 *= mk[7].x; v1 *= mk[7].y; }
                u[7] = make_float2(v0, v1);
            }
        }
    };
    if (fast) run(false); else run(true);         // block-uniform branch

    // ---- store valid region rel [16,112)^2: waves 2..13, lanes 8..55 ----
    if (w >= 2 && w < 14 && l >= 8 && l < 56) {
        float* oB = out + (size_t)b * IMG_P;
        if (fast) {
            #pragma unroll
            for (int r = 0; r < 8; ++r)
                *(float2*)(oB + (size_t)(gy0 + r) * Ni + c0) = u[r];
        } else {
            #pragma unroll
            for (int r = 0; r < 8; ++r) {
                const int gy = gy0 + r;
                if ((unsigned)gy < (unsigned)Ni) {
                    if ((unsigned)c0       < (unsigned)Ni) oB[(size_t)gy * Ni + c0]     = u[r].x;
                    if ((unsigned)(c0 + 1) < (unsigned)Ni) oB[(size_t)gy * Ni + c0 + 1] = u[r].y;
                }
            }
        }
    }
}

extern "C" void kernel_launch(void* const* d_in, const int* in_sizes, int n_in,
                              void* d_out, int out_size, void* d_ws, size_t ws_size,
                              hipStream_t stream)
{
    const float* pre = (const float*)d_in[0];
    const float* f   = (const float*)d_in[1];
    const float* kap = (const float*)d_in[2];
    float* out = (float*)d_out;
    (void)d_ws; (void)ws_size;                   // no intermediate buffer needed

    dim3 blk(1024, 1, 1);
    dim3 grd((Ni + TOUT - 1) / TOUT, (Ni + TOUT - 1) / TOUT, 8);   // 11 x 11 x 8

    jac_fused16<<<grd, blk, 0, stream>>>(pre, out, kap, f);
}

// Round 8
// 224.436 us; speedup vs baseline: 1.3600x; 1.3600x over previous
//
#include <hip/hip_runtime.h>

// Register-resident fused-16 Jacobi, v10: v7 + wave-pair peer-sync.
//  - v9 (wE contraction + masks + dual lambda) exploded scratch (WRITE 269MB,
//    211us) -> fully reverted. Re-audit of v7/v8: excess WRITE was only
//    ~6.5 dwords/thread TOTAL (0.25 TB/s) -> spill was never the bottleneck.
//  - Real residual: 16 full-block barriers x 16 waves. Each step convoys all
//    16 waves to the slowest; per-block time ~55us vs ~10us of VALU work.
//  - v10 removes __syncthreads from the step loop. Wave w only needs waves
//    w+-1: per step (1) write own boundary rows to dbuf LDS, (2) fence +
//    lane0 releases monotone flag[w]=t+1, (3) compute rows 1..6 (no neighbor
//    data) -- the wait hides here, (4) spin-acquire flag[w+-1] >= t+1,
//    (5) read hN/hS, (6) compute rows 0/7.
//    WAR-safe with the 2-buffer: our write@t+2 requires neighbor flag>=t+2,
//    which follows (program order) its read@t; symmetric for reads. Monotone
//    flags -> deadlock-free. One __syncthreads total (flag init).
//  - everything else identical to v7 (102.6us, verified): tile 128x128,
//    16 waves, lane owns 2 cols, rolling 3-row kappa window, explicit-wE
//    weights (OOB rows get all-zero weights -> u'=0, no masks), DPP W/E
//    (garbage halo-tight at cols 0/127), output rel [16,112)^2.

namespace {
constexpr int    G    = 1024, Ni = 1022;
constexpr int    TOUT = 96, HALO = 16;          // tile 128
constexpr size_t IMG_K = (size_t)G * G;
constexpr size_t IMG_P = (size_t)Ni * Ni;
constexpr float  H2 = (float)(1.0 / (1023.0 * 1023.0));
}

__device__ __forceinline__ float frcp(float x) { return __builtin_amdgcn_rcpf(x); }

// lane l <- lane l-1 (wave_shr1); shifted-in lane gets 0 (bound_ctrl)
__device__ __forceinline__ float lane_shr1(float x) {
    return __builtin_bit_cast(float,
        __builtin_amdgcn_update_dpp(0, __builtin_bit_cast(int, x), 0x138, 0xF, 0xF, true));
}
// lane l <- lane l+1 (wave_shl1)
__device__ __forceinline__ float lane_shl1(float x) {
    return __builtin_bit_cast(float,
        __builtin_amdgcn_update_dpp(0, __builtin_bit_cast(int, x), 0x130, 0xF, 0xF, true));
}

__global__ __launch_bounds__(1024)
void jac_fused16(const float* __restrict__ pre, float* __restrict__ out,
                 const float* __restrict__ kap, const float* __restrict__ fin)
{
    __shared__ float2 ex[2][2][1024];            // [buf][top/bot][tid] = 32 KB
    __shared__ int flg[16];                      // per-wave monotone step flag

    const int tid = threadIdx.x;
    const int w = tid >> 6, l = tid & 63;        // wave id (0..15), lane id
    const int bx = blockIdx.x, by = blockIdx.y, b = blockIdx.z;
    const int X0 = bx * TOUT - HALO, Y0 = by * TOUT - HALO;
    const int c0 = X0 + 2 * l;                   // lane's first column (even)
    const int gy0 = Y0 + 8 * w;                  // wave's first row

    const float* kB = kap + (size_t)b * IMG_K;
    const float* fB = fin + (size_t)b * IMG_K;
    const bool fast = (bx >= 1) && (bx <= 9) && (by >= 1) && (by <= 9);

    // ---- weights via rolling 3-row kappa window (transient peak ~10 regs) ----
    float2 wN[8], wS[8], wW[8], wE[8], Fc[8];
    if (fast) {                                  // all accesses in-bounds
        const float* kp = kB + (size_t)gy0 * G + c0;
        const float* fp = fB + (size_t)(gy0 + 1) * G + c0;
        float2 q0 = *(const float2*)kp;          // kappa row gy0,   cols c0,c0+1
        float2 q1 = *(const float2*)(kp + G);    // kappa row gy0+1
        float  e0 = lane_shl1(q0.x);             // kappa[gy0,   c0+2]
        float  e1 = lane_shl1(q1.x);             // kappa[gy0+1, c0+2]
        #pragma unroll
        for (int r = 0; r < 8; ++r) {
            const float2 q2 = *(const float2*)(kp + (size_t)(r + 2) * G);
            const float  e2 = lane_shl1(q2.x);
            const float2 fr = *(const float2*)(fp + (size_t)r * G);
            const float f0 = fr.y, f1 = lane_shl1(fr.x);
            const float ke1 = lane_shl1(q1.y);   // kappa[gy+1, c0+3]
            const float inv0 = frcp(2.0f * q1.y + 0.5f * (q0.y + q2.y + q1.x + e1));
            const float inv1 = frcp(2.0f * e1   + 0.5f * (e0 + e2 + q1.y + ke1));
            wN[r] = make_float2(0.5f * (q1.y + q0.y) * inv0, 0.5f * (e1 + e0) * inv1);
            wS[r] = make_float2(0.5f * (q1.y + q2.y) * inv0, 0.5f * (e1 + e2) * inv1);
            wW[r] = make_float2(0.5f * (q1.y + q1.x) * inv0, 0.5f * (e1 + q1.y) * inv1);
            wE[r] = make_float2(0.5f * (q1.y + e1)   * inv0, 0.5f * (e1 + ke1) * inv1);
            Fc[r] = make_float2(f0 * H2 * inv0, f1 * H2 * inv1);
            q0 = q1; q1 = q2; e0 = e1; e1 = e2;
        }
    } else {
        auto gk = [&](int ry, int cx) -> float {
            return ((unsigned)ry < (unsigned)G && (unsigned)cx < (unsigned)G)
                 ? kB[(size_t)ry * G + cx] : 0.0f;
        };
        float qx0 = gk(gy0,     c0), qy0 = gk(gy0,     c0 + 1);
        float qx1 = gk(gy0 + 1, c0), qy1 = gk(gy0 + 1, c0 + 1);
        float e0 = lane_shl1(qx0), e1 = lane_shl1(qx1);
        #pragma unroll
        for (int r = 0; r < 8; ++r) {
            const float qx2 = gk(gy0 + r + 2, c0), qy2 = gk(gy0 + r + 2, c0 + 1);
            const float e2 = lane_shl1(qx2);
            const int ry = gy0 + 1 + r;
            const bool rv = (unsigned)ry < (unsigned)G;
            const float fa = (rv && (unsigned)c0       < (unsigned)G) ? fB[(size_t)ry * G + c0]     : 0.0f;
            const float fb = (rv && (unsigned)(c0 + 1) < (unsigned)G) ? fB[(size_t)ry * G + c0 + 1] : 0.0f;
            const float f0 = fb, f1 = lane_shl1(fa);
            const float ke1 = lane_shl1(qy1);
            const float inv0 = frcp(2.0f * qy1 + 0.5f * (qy0 + qy2 + qx1 + e1));
            const float inv1 = frcp(2.0f * e1  + 0.5f * (e0 + e2 + qy1 + ke1));
            const int gy = gy0 + r;
            const bool dr = (unsigned)gy < (unsigned)Ni;
            const bool d0 = dr && (unsigned)c0       < (unsigned)Ni;
            const bool d1 = dr && (unsigned)(c0 + 1) < (unsigned)Ni;
            wN[r] = make_float2(d0 ? 0.5f * (qy1 + qy0) * inv0 : 0.0f,
                                d1 ? 0.5f * (e1 + e0)   * inv1 : 0.0f);
            wS[r] = make_float2(d0 ? 0.5f * (qy1 + qy2) * inv0 : 0.0f,
                                d1 ? 0.5f * (e1 + e2)   * inv1 : 0.0f);
            wW[r] = make_float2(d0 ? 0.5f * (qy1 + qx1) * inv0 : 0.0f,
                                d1 ? 0.5f * (e1 + qy1)  * inv1 : 0.0f);
            wE[r] = make_float2(d0 ? 0.5f * (qy1 + e1)  * inv0 : 0.0f,
                                d1 ? 0.5f * (e1 + ke1)  * inv1 : 0.0f);
            Fc[r] = make_float2(d0 ? f0 * H2 * inv0 : 0.0f,
                                d1 ? f1 * H2 * inv1 : 0.0f);
            qx0 = qx1; qy0 = qy1; qx1 = qx2; qy1 = qy2; e0 = e1; e1 = e2;
        }
    }

    // ---- u patch (loaded after weights: kappa/f transients are dead) ----
    float2 u[8];
    if (fast) {
        const float* uS = pre + (size_t)b * IMG_P + (size_t)gy0 * Ni + c0;
        #pragma unroll
        for (int r = 0; r < 8; ++r) u[r] = *(const float2*)(uS + (size_t)r * Ni);
    } else {
        const float* uS = pre + (size_t)b * IMG_P;
        #pragma unroll
        for (int r = 0; r < 8; ++r) {
            const int gy = gy0 + r;
            const bool rv = (unsigned)gy < (unsigned)Ni;
            const float a = (rv && (unsigned)c0       < (unsigned)Ni) ? uS[(size_t)gy * Ni + c0]     : 0.0f;
            const float q = (rv && (unsigned)(c0 + 1) < (unsigned)Ni) ? uS[(size_t)gy * Ni + c0 + 1] : 0.0f;
            u[r] = make_float2(a, q);
        }
    }

    // ---- 16 steps, NO block barrier: wave-pair peer-sync via LDS flags ----
    const int iN = (w > 0)  ? tid - 64 : tid;     // wave w-1's bottom row (clamp: halo-safe)
    const int iS = (w < 15) ? tid + 64 : tid;     // wave w+1's top row
    if (l == 0) flg[w] = 0;
    __syncthreads();                              // flag init visible to all

    #pragma unroll
    for (int t = 0; t < 16; ++t) {
        float2* top = ex[t & 1][0];
        float2* bot = ex[t & 1][1];
        top[tid] = u[0];                          // (1) publish own step-t rows
        bot[tid] = u[7];
        __threadfence_block();                    // (2) drain, then release flag
        if (l == 0)
            __hip_atomic_store(&flg[w], t + 1, __ATOMIC_RELEASE, __HIP_MEMORY_SCOPE_WORKGROUP);

        const float2 o1s = u[1], o6s = u[6];      // old values for rows 0/7
        float2 pn = u[0];
        #pragma unroll
        for (int r = 1; r < 7; ++r) {             // (3) register-only rows: wait hides here
            const float2 s = u[r + 1];            // old (ascending order)
            const float o0 = u[r].x, o1 = u[r].y;
            const float uW = lane_shr1(o1);
            const float uE = lane_shl1(o0);
            const float v0 = fmaf(wN[r].x, pn.x,
                             fmaf(wS[r].x, s.x,
                             fmaf(wW[r].x, uW,
                             fmaf(wE[r].x, o1, Fc[r].x))));
            const float v1 = fmaf(wN[r].y, pn.y,
                             fmaf(wS[r].y, s.y,
                             fmaf(wW[r].y, o0,
                             fmaf(wE[r].y, uE, Fc[r].y))));
            pn = make_float2(o0, o1);
            u[r] = make_float2(v0, v1);
        }
        // (4) acquire neighbors' step-t rows
        if (w > 0)
            while (__hip_atomic_load(&flg[w - 1], __ATOMIC_ACQUIRE, __HIP_MEMORY_SCOPE_WORKGROUP) <= t) {}
        if (w < 15)
            while (__hip_atomic_load(&flg[w + 1], __ATOMIC_ACQUIRE, __HIP_MEMORY_SCOPE_WORKGROUP) <= t) {}
        const float2 hN = bot[iN];                // (5)
        const float2 hS = top[iS];
        {   // (6) row 0: N = hN, S = old u[1]
            const float o0 = u[0].x, o1 = u[0].y;
            const float uW = lane_shr1(o1);
            const float uE = lane_shl1(o0);
            u[0].x = fmaf(wN[0].x, hN.x,
                     fmaf(wS[0].x, o1s.x,
                     fmaf(wW[0].x, uW,
                     fmaf(wE[0].x, o1, Fc[0].x))));
            u[0].y = fmaf(wN[0].y, hN.y,
                     fmaf(wS[0].y, o1s.y,
                     fmaf(wW[0].y, o0,
                     fmaf(wE[0].y, uE, Fc[0].y))));
        }
        {   // row 7: N = old u[6], S = hS
            const float o0 = u[7].x, o1 = u[7].y;
            const float uW = lane_shr1(o1);
            const float uE = lane_shl1(o0);
            u[7].x = fmaf(wN[7].x, o6s.x,
                     fmaf(wS[7].x, hS.x,
                     fmaf(wW[7].x, uW,
                     fmaf(wE[7].x, o1, Fc[7].x))));
            u[7].y = fmaf(wN[7].y, o6s.y,
                     fmaf(wS[7].y, hS.y,
                     fmaf(wW[7].y, o0,
                     fmaf(wE[7].y, uE, Fc[7].y))));
        }
    }

    // ---- store valid region rel [16,112)^2: waves 2..13, lanes 8..55 ----
    if (w >= 2 && w < 14 && l >= 8 && l < 56) {
        float* oB = out + (size_t)b * IMG_P;
        if (fast) {
            #pragma unroll
            for (int r = 0; r < 8; ++r)
                *(float2*)(oB + (size_t)(gy0 + r) * Ni + c0) = u[r];
        } else {
            #pragma unroll
            for (int r = 0; r < 8; ++r) {
                const int gy = gy0 + r;
                if ((unsigned)gy < (unsigned)Ni) {
                    if ((unsigned)c0       < (unsigned)Ni) oB[(size_t)gy * Ni + c0]     = u[r].x;
                    if ((unsigned)(c0 + 1) < (unsigned)Ni) oB[(size_t)gy * Ni + c0 + 1] = u[r].y;
                }
            }
        }
    }
}

extern "C" void kernel_launch(void* const* d_in, const int* in_sizes, int n_in,
                              void* d_out, int out_size, void* d_ws, size_t ws_size,
                              hipStream_t stream)
{
    const float* pre = (const float*)d_in[0];
    const float* f   = (const float*)d_in[1];
    const float* kap = (const float*)d_in[2];
    float* out = (float*)d_out;
    (void)d_ws; (void)ws_size;                   // no intermediate buffer needed

    dim3 blk(1024, 1, 1);
    dim3 grd((Ni + TOUT - 1) / TOUT, (Ni + TOUT - 1) / TOUT, 8);   // 11 x 11 x 8

    jac_fused16<<<grd, blk, 0, stream>>>(pre, out, kap, f);
}

// Round 10
// 200.894 us; speedup vs baseline: 1.5194x; 1.1172x over previous
//
#include <hip/hip_runtime.h>

// Register-resident fused-16 Jacobi, v12: v7-exact + packed-FMA step loop.
//  - v9/v10/v11 all failed or regressed (scratch blowup / peer-sync / NaN).
//    Reset to the verified v7 (102.6us, passed) and change ONE thing.
//  - Rate wall across v5-v8: ~2.4M point-steps/us (~65 lane-cyc/pt vs ~10
//    static ops), VALU 39-55%, HBM 25%, occ 35% -> issue-count + dep stalls.
//  - v12 rewrites ONLY the step arithmetic on ext_vector float2 so the
//    backend can emit v_pk_fma_f32 (2 FMAs/instr on CDNA): 4 pk_fma replace
//    8 scalar FMAs per row-pair. Cross W/E terms vectorize as
//    uW_vec={shr(o.y), o.x}, uE_vec={o.y, shl(o.x)} (1 DPP + 1 mov each).
//    Identical math, identical memory behavior; worst case the compiler
//    scalarizes and we get v7 back.
//  - everything else verbatim v7: tile 128x128, 16 waves, lane owns 2 cols,
//    rolling 3-row kappa window for weights (explicit wE; OOB points get
//    all-zero weights -> u'=0, no masks), DPP kappa garbage lands at tile
//    cols 0/127 (discard-halo tight for 16 steps), dbuf LDS strip exchange
//    (32KB), one barrier/step, output rel [16,112)^2.

namespace {
constexpr int    G    = 1024, Ni = 1022;
constexpr int    TOUT = 96, HALO = 16;          // tile 128
constexpr size_t IMG_K = (size_t)G * G;
constexpr size_t IMG_P = (size_t)Ni * Ni;
constexpr float  H2 = (float)(1.0 / (1023.0 * 1023.0));
}

typedef float v2f __attribute__((ext_vector_type(2)));

__device__ __forceinline__ float frcp(float x) { return __builtin_amdgcn_rcpf(x); }

// lane l <- lane l-1 (wave_shr1); shifted-in lane gets 0 (bound_ctrl)
__device__ __forceinline__ float lane_shr1(float x) {
    return __builtin_bit_cast(float,
        __builtin_amdgcn_update_dpp(0, __builtin_bit_cast(int, x), 0x138, 0xF, 0xF, true));
}
// lane l <- lane l+1 (wave_shl1)
__device__ __forceinline__ float lane_shl1(float x) {
    return __builtin_bit_cast(float,
        __builtin_amdgcn_update_dpp(0, __builtin_bit_cast(int, x), 0x130, 0xF, 0xF, true));
}

__global__ __launch_bounds__(1024, 4)
void jac_fused16(const float* __restrict__ pre, float* __restrict__ out,
                 const float* __restrict__ kap, const float* __restrict__ fin)
{
    __shared__ float2 ex[2][2][1024];            // [buf][top/bot][tid] = 32 KB

    const int tid = threadIdx.x;
    const int w = tid >> 6, l = tid & 63;        // wave id (0..15), lane id
    const int bx = blockIdx.x, by = blockIdx.y, b = blockIdx.z;
    const int X0 = bx * TOUT - HALO, Y0 = by * TOUT - HALO;
    const int c0 = X0 + 2 * l;                   // lane's first column (even)
    const int gy0 = Y0 + 8 * w;                  // wave's first row

    const float* kB = kap + (size_t)b * IMG_K;
    const float* fB = fin + (size_t)b * IMG_K;
    const bool fast = (bx >= 1) && (bx <= 9) && (by >= 1) && (by <= 9);

    // ---- weights via rolling 3-row kappa window (v7 verbatim, v2f storage) ----
    v2f wN[8], wS[8], wW[8], wE[8], Fc[8];
    if (fast) {                                  // all accesses in-bounds
        const float* kp = kB + (size_t)gy0 * G + c0;
        const float* fp = fB + (size_t)(gy0 + 1) * G + c0;
        float2 q0 = *(const float2*)kp;          // kappa row gy0,   cols c0,c0+1
        float2 q1 = *(const float2*)(kp + G);    // kappa row gy0+1
        float  e0 = lane_shl1(q0.x);             // kappa[gy0,   c0+2]
        float  e1 = lane_shl1(q1.x);             // kappa[gy0+1, c0+2]
        #pragma unroll
        for (int r = 0; r < 8; ++r) {
            const float2 q2 = *(const float2*)(kp + (size_t)(r + 2) * G);
            const float  e2 = lane_shl1(q2.x);
            const float2 fr = *(const float2*)(fp + (size_t)r * G);
            const float f0 = fr.y, f1 = lane_shl1(fr.x);
            const float ke1 = lane_shl1(q1.y);   // kappa[gy+1, c0+3]
            const float inv0 = frcp(2.0f * q1.y + 0.5f * (q0.y + q2.y + q1.x + e1));
            const float inv1 = frcp(2.0f * e1   + 0.5f * (e0 + e2 + q1.y + ke1));
            wN[r] = v2f{0.5f * (q1.y + q0.y) * inv0, 0.5f * (e1 + e0) * inv1};
            wS[r] = v2f{0.5f * (q1.y + q2.y) * inv0, 0.5f * (e1 + e2) * inv1};
            wW[r] = v2f{0.5f * (q1.y + q1.x) * inv0, 0.5f * (e1 + q1.y) * inv1};
            wE[r] = v2f{0.5f * (q1.y + e1)   * inv0, 0.5f * (e1 + ke1) * inv1};
            Fc[r] = v2f{f0 * H2 * inv0, f1 * H2 * inv1};
            q0 = q1; q1 = q2; e0 = e1; e1 = e2;
        }
    } else {
        auto gk = [&](int ry, int cx) -> float {
            return ((unsigned)ry < (unsigned)G && (unsigned)cx < (unsigned)G)
                 ? kB[(size_t)ry * G + cx] : 0.0f;
        };
        float qx0 = gk(gy0,     c0), qy0 = gk(gy0,     c0 + 1);
        float qx1 = gk(gy0 + 1, c0), qy1 = gk(gy0 + 1, c0 + 1);
        float e0 = lane_shl1(qx0), e1 = lane_shl1(qx1);
        #pragma unroll
        for (int r = 0; r < 8; ++r) {
            const float qx2 = gk(gy0 + r + 2, c0), qy2 = gk(gy0 + r + 2, c0 + 1);
            const float e2 = lane_shl1(qx2);
            const int ry = gy0 + 1 + r;
            const bool rv = (unsigned)ry < (unsigned)G;
            const float fa = (rv && (unsigned)c0       < (unsigned)G) ? fB[(size_t)ry * G + c0]     : 0.0f;
            const float fb = (rv && (unsigned)(c0 + 1) < (unsigned)G) ? fB[(size_t)ry * G + c0 + 1] : 0.0f;
            const float f0 = fb, f1 = lane_shl1(fa);
            const float ke1 = lane_shl1(qy1);
            const float inv0 = frcp(2.0f * qy1 + 0.5f * (qy0 + qy2 + qx1 + e1));
            const float inv1 = frcp(2.0f * e1  + 0.5f * (e0 + e2 + qy1 + ke1));
            const int gy = gy0 + r;
            const bool dr = (unsigned)gy < (unsigned)Ni;
            const bool d0 = dr && (unsigned)c0       < (unsigned)Ni;
            const bool d1 = dr && (unsigned)(c0 + 1) < (unsigned)Ni;
            wN[r] = v2f{d0 ? 0.5f * (qy1 + qy0) * inv0 : 0.0f,
                        d1 ? 0.5f * (e1 + e0)   * inv1 : 0.0f};
            wS[r] = v2f{d0 ? 0.5f * (qy1 + qy2) * inv0 : 0.0f,
                        d1 ? 0.5f * (e1 + e2)   * inv1 : 0.0f};
            wW[r] = v2f{d0 ? 0.5f * (qy1 + qx1) * inv0 : 0.0f,
                        d1 ? 0.5f * (e1 + qy1)  * inv1 : 0.0f};
            wE[r] = v2f{d0 ? 0.5f * (qy1 + e1)  * inv0 : 0.0f,
                        d1 ? 0.5f * (e1 + ke1)  * inv1 : 0.0f};
            Fc[r] = v2f{d0 ? f0 * H2 * inv0 : 0.0f,
                        d1 ? f1 * H2 * inv1 : 0.0f};
            qx0 = qx1; qy0 = qy1; qx1 = qx2; qy1 = qy2; e0 = e1; e1 = e2;
        }
    }

    // ---- u patch (loaded after weights: kappa/f transients are dead) ----
    v2f u[8];
    if (fast) {
        const float* uS = pre + (size_t)b * IMG_P + (size_t)gy0 * Ni + c0;
        #pragma unroll
        for (int r = 0; r < 8; ++r) {
            const float2 q = *(const float2*)(uS + (size_t)r * Ni);
            u[r] = v2f{q.x, q.y};
        }
    } else {
        const float* uS = pre + (size_t)b * IMG_P;
        #pragma unroll
        for (int r = 0; r < 8; ++r) {
            const int gy = gy0 + r;
            const bool rv = (unsigned)gy < (unsigned)Ni;
            const float a = (rv && (unsigned)c0       < (unsigned)Ni) ? uS[(size_t)gy * Ni + c0]     : 0.0f;
            const float q = (rv && (unsigned)(c0 + 1) < (unsigned)Ni) ? uS[(size_t)gy * Ni + c0 + 1] : 0.0f;
            u[r] = v2f{a, q};
        }
    }

    // ---- 16 steps (v7 order); packed-FMA row updates ----
    const int iN = (w > 0)  ? tid - 64 : tid;     // wave w-1's bottom row (clamp: halo-safe)
    const int iS = (w < 15) ? tid + 64 : tid;     // wave w+1's top row
    #pragma unroll
    for (int t = 0; t < 16; ++t) {
        float2* top = ex[t & 1][0];
        float2* bot = ex[t & 1][1];
        top[tid] = make_float2(u[0].x, u[0].y);
        bot[tid] = make_float2(u[7].x, u[7].y);
        __syncthreads();
        const float2 hNq = bot[iN];
        const float2 hSq = top[iS];
        const v2f hS = v2f{hSq.x, hSq.y};
        v2f pn = v2f{hNq.x, hNq.y};
        #pragma unroll
        for (int r = 0; r < 8; ++r) {
            const v2f s = (r < 7) ? u[r + 1] : hS;   // old value (not yet overwritten)
            const v2f o = u[r];
            const float uWs = lane_shr1(o.y);        // prev lane's col1 = W of col0
            const float uEs = lane_shl1(o.x);        // next lane's col0 = E of col1
            const v2f uWv = v2f{uWs, o.x};
            const v2f uEv = v2f{o.y, uEs};
            v2f v = __builtin_elementwise_fma(wN[r], pn, Fc[r]);
            v = __builtin_elementwise_fma(wS[r], s,   v);
            v = __builtin_elementwise_fma(wW[r], uWv, v);
            v = __builtin_elementwise_fma(wE[r], uEv, v);
            pn = o;
            u[r] = v;
        }
    }

    // ---- store valid region rel [16,112)^2: waves 2..13, lanes 8..55 ----
    if (w >= 2 && w < 14 && l >= 8 && l < 56) {
        float* oB = out + (size_t)b * IMG_P;
        if (fast) {
            #pragma unroll
            for (int r = 0; r < 8; ++r)
                *(float2*)(oB + (size_t)(gy0 + r) * Ni + c0) = make_float2(u[r].x, u[r].y);
        } else {
            #pragma unroll
            for (int r = 0; r < 8; ++r) {
                const int gy = gy0 + r;
                if ((unsigned)gy < (unsigned)Ni) {
                    if ((unsigned)c0       < (unsigned)Ni) oB[(size_t)gy * Ni + c0]     = u[r].x;
                    if ((unsigned)(c0 + 1) < (unsigned)Ni) oB[(size_t)gy * Ni + c0 + 1] = u[r].y;
                }
            }
        }
    }
}

extern "C" void kernel_launch(void* const* d_in, const int* in_sizes, int n_in,
                              void* d_out, int out_size, void* d_ws, size_t ws_size,
                              hipStream_t stream)
{
    const float* pre = (const float*)d_in[0];
    const float* f   = (const float*)d_in[1];
    const float* kap = (const float*)d_in[2];
    float* out = (float*)d_out;
    (void)d_ws; (void)ws_size;                   // no intermediate buffer needed

    dim3 blk(1024, 1, 1);
    dim3 grd((Ni + TOUT - 1) / TOUT, (Ni + TOUT - 1) / TOUT, 8);   // 11 x 11 x 8

    jac_fused16<<<grd, blk, 0, stream>>>(pre, out, kap, f);
}